// Round 2
// baseline (276470.483 us; speedup 1.0000x reference)
//
#include <hip/hip_runtime.h>

#define HID 512
#define NB  64
#define NT  1024
#define THX 0.1f
#define THH 0.05f

// ---- prep: transpose W_ih_l0 (1536x6 f32) -> [6][1536] f32 ----
__global__ void transpose_ih0(const float* __restrict__ src, float* __restrict__ dst) {
    int idx = blockIdx.x * blockDim.x + threadIdx.x;
    const int total = 1536 * 6;
    if (idx < total) {
        int r = idx / 6, c = idx % 6;          // src[r][c]
        dst[c * 1536 + r] = src[idx];
    }
}

// ---- prep: transpose a 1536x512 f32 matrix -> [512][1536] f32 ----
__global__ void transpose_hf(const float* __restrict__ src, float* __restrict__ dst) {
    int idx = blockIdx.x * blockDim.x + threadIdx.x;
    const int total = 1536 * HID;
    if (idx < total) {
        int r = idx / HID, c = idx % HID;      // src[r][c]
        dst[c * 1536 + r] = src[idx];
    }
}

// ---- main persistent kernel: one workgroup per batch element ----
// FAST: weights pre-transposed to [k][1536] f32 in d_ws (coalesced).
// !FAST: read original row-major f32 weights directly (fallback if ws too small).
template <bool FAST>
__global__ __launch_bounds__(512)
void dgru_kernel(const float* __restrict__ x,
                 const float* __restrict__ wih0,    // FAST: [6][1536] ; RAW: [1536][6]
                 const float* __restrict__ whh0,    // FAST: [512][1536] ; RAW: [1536][512]
                 const float* __restrict__ wih1,
                 const float* __restrict__ whh1,
                 const float* __restrict__ bih0, const float* __restrict__ bhh0,
                 const float* __restrict__ bih1, const float* __restrict__ bhh1,
                 const float* __restrict__ wfc,  const float* __restrict__ bfc,
                 float* __restrict__ out) {
    __shared__ float s_dx0[8];
    __shared__ float s_xp0[8];
    __shared__ float s_dh0[HID];
    __shared__ float s_dx1[HID];
    __shared__ float s_dh1[HID];
    __shared__ float s_part[16];

    const int j = threadIdx.x;   // hidden unit owned by this thread
    const int b = blockIdx.x;    // batch element owned by this workgroup

    // recurrent state (registers)
    float h0 = 0.f, h0p = 0.f, xp1 = 0.f, h1 = 0.f, h1p = 0.f;
    // dm carries: r,z get b_ih+b_hh; n gets b_ih; dm_nh gets b_hh[2H:]
    float cr0 = bih0[j]         + bhh0[j];
    float cz0 = bih0[HID + j]   + bhh0[HID + j];
    float cn0 = bih0[2*HID + j];
    float cnh0 = bhh0[2*HID + j];
    float cr1 = bih1[j]         + bhh1[j];
    float cz1 = bih1[HID + j]   + bhh1[HID + j];
    float cn1 = bih1[2*HID + j];
    float cnh1 = bhh1[2*HID + j];

    if (j < 8) { s_xp0[j] = 0.f; s_dx0[j] = 0.f; }

    const float wfc0 = wfc[j];
    const float wfc1 = wfc[HID + j];

    __syncthreads();

    for (int t = 0; t < NT; ++t) {
        // ---- A: layer0 deltas (dh on h-state; dx on expanded input features) ----
        float d = h0 - h0p;
        if (fabsf(d) < THH) d = 0.f; else h0p = h0;
        s_dh0[j] = d;
        if (j < 6) {
            float iv = x[(b * NT + t) * 2 + 0];
            float qv = x[(b * NT + t) * 2 + 1];
            float amp = sqrtf(iv * iv + qv * qv);
            float f;
            if      (j == 0) f = iv;
            else if (j == 1) f = qv;
            else if (j == 2) f = amp;
            else if (j == 3) f = amp * amp * amp;
            else if (j == 4) f = qv / amp;
            else             f = iv / amp;
            float dx = f - s_xp0[j];
            if (fabsf(dx) < THX) dx = 0.f; else s_xp0[j] = f;
            s_dx0[j] = dx;
        }
        __syncthreads();

        // ---- B: layer0 MAC + gates ----
        {
            float ar = cr0, az = cz0, an = cn0, anh = cnh0;
            #pragma unroll
            for (int f = 0; f < 6; ++f) {
                float dv = s_dx0[f];
                if (dv != 0.f) {   // block-uniform branch (LDS broadcast)
                    if (FAST) {
                        const float* w = wih0 + f * 1536;
                        ar += dv * w[j]; az += dv * w[HID + j]; an += dv * w[2*HID + j];
                    } else {
                        ar += dv * wih0[j * 6 + f];
                        az += dv * wih0[(HID + j) * 6 + f];
                        an += dv * wih0[(2*HID + j) * 6 + f];
                    }
                }
            }
            #pragma unroll 4
            for (int k = 0; k < HID; ++k) {
                float dv = s_dh0[k];
                if (dv != 0.f) {   // skip loads + FMAs when delta is zero
                    if (FAST) {
                        const float* w = whh0 + k * 1536;
                        ar  += dv * w[j];
                        az  += dv * w[HID + j];
                        anh += dv * w[2*HID + j];
                    } else {
                        ar  += dv * whh0[j * HID + k];
                        az  += dv * whh0[(HID + j) * HID + k];
                        anh += dv * whh0[(2*HID + j) * HID + k];
                    }
                }
            }
            cr0 = ar; cz0 = az; cn0 = an; cnh0 = anh;
            float r = 1.f / (1.f + expf(-ar));
            float z = 1.f / (1.f + expf(-az));
            float n = tanhf(an + r * anh);
            h0 = (1.f - z) * n + z * h0;
        }

        // ---- C: layer1 deltas ----
        float dxv = h0 - xp1;
        if (fabsf(dxv) < THX) dxv = 0.f; else xp1 = h0;
        s_dx1[j] = dxv;
        float dhv = h1 - h1p;
        if (fabsf(dhv) < THH) dhv = 0.f; else h1p = h1;
        s_dh1[j] = dhv;
        __syncthreads();

        // ---- D: layer1 MAC + gates ----
        {
            float ar = cr1, az = cz1, an = cn1, anh = cnh1;
            #pragma unroll 4
            for (int k = 0; k < HID; ++k) {
                float dv = s_dx1[k];
                if (dv != 0.f) {
                    if (FAST) {
                        const float* w = wih1 + k * 1536;
                        ar += dv * w[j];
                        az += dv * w[HID + j];
                        an += dv * w[2*HID + j];
                    } else {
                        ar += dv * wih1[j * HID + k];
                        az += dv * wih1[(HID + j) * HID + k];
                        an += dv * wih1[(2*HID + j) * HID + k];
                    }
                }
            }
            #pragma unroll 4
            for (int k = 0; k < HID; ++k) {
                float dv = s_dh1[k];
                if (dv != 0.f) {
                    if (FAST) {
                        const float* w = whh1 + k * 1536;
                        ar  += dv * w[j];
                        az  += dv * w[HID + j];
                        anh += dv * w[2*HID + j];
                    } else {
                        ar  += dv * whh1[j * HID + k];
                        az  += dv * whh1[(HID + j) * HID + k];
                        anh += dv * whh1[(2*HID + j) * HID + k];
                    }
                }
            }
            cr1 = ar; cz1 = az; cn1 = an; cnh1 = anh;
            float r = 1.f / (1.f + expf(-ar));
            float z = 1.f / (1.f + expf(-az));
            float n = tanhf(an + r * anh);
            h1 = (1.f - z) * n + z * h1;
        }

        // ---- E: FC head (2 outputs) ----
        float p0 = h1 * wfc0, p1 = h1 * wfc1;
        #pragma unroll
        for (int off = 32; off > 0; off >>= 1) {
            p0 += __shfl_down(p0, off, 64);
            p1 += __shfl_down(p1, off, 64);
        }
        if ((j & 63) == 0) { s_part[(j >> 6) * 2] = p0; s_part[(j >> 6) * 2 + 1] = p1; }
        __syncthreads();
        if (j == 0) {
            float o0 = bfc[0], o1 = bfc[1];
            #pragma unroll
            for (int w2 = 0; w2 < 8; ++w2) { o0 += s_part[w2 * 2]; o1 += s_part[w2 * 2 + 1]; }
            out[(b * NT + t) * 2 + 0] = o0;
            out[(b * NT + t) * 2 + 1] = o1;
        }
        __syncthreads();  // protect s_part / LDS arrays before next iteration
    }
}

extern "C" void kernel_launch(void* const* d_in, const int* in_sizes, int n_in,
                              void* d_out, int out_size, void* d_ws, size_t ws_size,
                              hipStream_t stream) {
    const float* x    = (const float*)d_in[0];
    // d_in[1] = h_0 : unused by the reference (it zero-inits h)
    const float* wih0 = (const float*)d_in[2];
    const float* whh0 = (const float*)d_in[3];
    const float* bih0 = (const float*)d_in[4];
    const float* bhh0 = (const float*)d_in[5];
    const float* wih1 = (const float*)d_in[6];
    const float* whh1 = (const float*)d_in[7];
    const float* bih1 = (const float*)d_in[8];
    const float* bhh1 = (const float*)d_in[9];
    const float* wfc  = (const float*)d_in[10];
    const float* bfc  = (const float*)d_in[11];
    float* out = (float*)d_out;

    const size_t MAT = (size_t)1536 * HID * sizeof(float);   // 3,145,728 B
    const size_t o_ih0 = 0;                                   // 6*1536*4 = 36,864 B
    const size_t o_hh0 = 36864;
    const size_t o_ih1 = o_hh0 + MAT;
    const size_t o_hh1 = o_ih1 + MAT;
    const size_t need  = o_hh1 + MAT;                         // ~9.04 MiB

    if (ws_size >= need) {
        float* wt_ih0 = (float*)((char*)d_ws + o_ih0);
        float* wt_hh0 = (float*)((char*)d_ws + o_hh0);
        float* wt_ih1 = (float*)((char*)d_ws + o_ih1);
        float* wt_hh1 = (float*)((char*)d_ws + o_hh1);
        transpose_ih0<<<(1536 * 6 + 255) / 256, 256, 0, stream>>>(wih0, wt_ih0);
        transpose_hf<<<(1536 * HID + 255) / 256, 256, 0, stream>>>(whh0, wt_hh0);
        transpose_hf<<<(1536 * HID + 255) / 256, 256, 0, stream>>>(wih1, wt_ih1);
        transpose_hf<<<(1536 * HID + 255) / 256, 256, 0, stream>>>(whh1, wt_hh1);
        dgru_kernel<true><<<NB, HID, 0, stream>>>(x, wt_ih0, wt_hh0, wt_ih1, wt_hh1,
                                                  bih0, bhh0, bih1, bhh1, wfc, bfc, out);
    } else {
        dgru_kernel<false><<<NB, HID, 0, stream>>>(x, wih0, whh0, wih1, whh1,
                                                   bih0, bhh0, bih1, bhh1, wfc, bfc, out);
    }
}

// Round 3
// 69870.203 us; speedup vs baseline: 3.9569x; 3.9569x over previous
//
#include <hip/hip_runtime.h>

#define HID 512
#define NB  64
#define NT  1024
#define THX 0.1f
#define THH 0.05f

// ---- prep: pack W_ih_l0 [1536][6] f32 -> [6][512][4] f32 (r,z,n,0 per j) ----
__global__ void pack_ih0(const float* __restrict__ src, float* __restrict__ dst) {
    int idx = blockIdx.x * blockDim.x + threadIdx.x;
    if (idx < 6 * HID) {
        int f = idx / HID, j = idx % HID;
        dst[f * 2048 + j * 4 + 0] = src[(0 * HID + j) * 6 + f];
        dst[f * 2048 + j * 4 + 1] = src[(1 * HID + j) * 6 + f];
        dst[f * 2048 + j * 4 + 2] = src[(2 * HID + j) * 6 + f];
        dst[f * 2048 + j * 4 + 3] = 0.f;
    }
}

// ---- prep: pack a [1536][512] f32 matrix -> [512(k)][512(j)][4] f32 ----
// slot 0/1/2 = rows j, 512+j, 1024+j (gates r, z, n-or-nh); slot 3 = pad.
__global__ void pack_h4(const float* __restrict__ src, float* __restrict__ dst) {
    int idx = blockIdx.x * blockDim.x + threadIdx.x;
    if (idx < HID * HID) {
        int k = idx / HID, j = idx % HID;
        dst[k * 2048 + j * 4 + 0] = src[(0 * HID + j) * HID + k];
        dst[k * 2048 + j * 4 + 1] = src[(1 * HID + j) * HID + k];
        dst[k * 2048 + j * 4 + 2] = src[(2 * HID + j) * HID + k];
        dst[k * 2048 + j * 4 + 3] = 0.f;
    }
}

// ---- main persistent kernel: one workgroup (512 thr) per batch element ----
// FAST: packed float4 weights in d_ws + compacted nnz MAC loops.
// !FAST: original row-major f32 weights, compacted loops with strided loads.
template <bool FAST>
__global__ __launch_bounds__(512)
void dgru_kernel(const float* __restrict__ x,
                 const float* __restrict__ wih0,
                 const float* __restrict__ whh0,
                 const float* __restrict__ wih1,
                 const float* __restrict__ whh1,
                 const float* __restrict__ bih0, const float* __restrict__ bhh0,
                 const float* __restrict__ bih1, const float* __restrict__ bhh1,
                 const float* __restrict__ wfc,  const float* __restrict__ bfc,
                 float* __restrict__ out) {
    __shared__ float s_dx0[8];
    __shared__ float s_xp0[8];
    __shared__ int   s_cnt[3][8];
    __shared__ int   s_idxA[HID];  __shared__ float s_valA[HID];   // layer0 dh
    __shared__ int   s_idxB[HID];  __shared__ float s_valB[HID];   // layer1 dx
    __shared__ int   s_idxC[HID];  __shared__ float s_valC[HID];   // layer1 dh
    __shared__ float s_part[16];

    const int j    = threadIdx.x;
    const int lane = j & 63;
    const int wid  = j >> 6;
    const int b    = blockIdx.x;

    float h0 = 0.f, h0p = 0.f, xp1 = 0.f, h1 = 0.f, h1p = 0.f;
    float cr0 = bih0[j]       + bhh0[j];
    float cz0 = bih0[HID + j] + bhh0[HID + j];
    float cn0 = bih0[2*HID + j];
    float cnh0 = bhh0[2*HID + j];
    float cr1 = bih1[j]       + bhh1[j];
    float cz1 = bih1[HID + j] + bhh1[HID + j];
    float cn1 = bih1[2*HID + j];
    float cnh1 = bhh1[2*HID + j];

    if (j < 8) { s_xp0[j] = 0.f; s_dx0[j] = 0.f; }

    const float wfc0 = wfc[j];
    const float wfc1 = wfc[HID + j];

    __syncthreads();

    for (int t = 0; t < NT; ++t) {
        // ---- layer0 deltas ----
        float d = h0 - h0p;
        if (fabsf(d) < THH) d = 0.f; else h0p = h0;
        unsigned long long mA = __ballot(d != 0.f);
        if (lane == 0) s_cnt[0][wid] = __popcll(mA);
        if (j < 6) {
            float iv = x[(b * NT + t) * 2 + 0];
            float qv = x[(b * NT + t) * 2 + 1];
            float amp = sqrtf(iv * iv + qv * qv);
            float f;
            if      (j == 0) f = iv;
            else if (j == 1) f = qv;
            else if (j == 2) f = amp;
            else if (j == 3) f = amp * amp * amp;
            else if (j == 4) f = qv / amp;
            else             f = iv / amp;
            float dx = f - s_xp0[j];
            if (fabsf(dx) < THX) dx = 0.f; else s_xp0[j] = f;
            s_dx0[j] = dx;
        }
        __syncthreads();                                   // S1
        int baseA = 0, nnzA = 0;
        #pragma unroll
        for (int w = 0; w < 8; ++w) {
            int c = s_cnt[0][w];
            baseA += (w < wid) ? c : 0;
            nnzA += c;
        }
        if (d != 0.f) {
            int pos = baseA + __popcll(mA & ((1ull << lane) - 1));
            s_idxA[pos] = j; s_valA[pos] = d;
        }
        __syncthreads();                                   // S2

        // ---- layer0 MAC + gates ----
        {
            float ar = cr0, az = cz0, an = cn0, anh = cnh0;
            if (FAST) {
                const float4* wp = (const float4*)wih0;    // [6][512]
                #pragma unroll
                for (int f = 0; f < 6; ++f) {
                    float dv = s_dx0[f];                   // dv==0 adds exact 0
                    float4 w = wp[f * HID + j];
                    ar += dv * w.x; az += dv * w.y; an += dv * w.z;
                }
                const float4* hp = (const float4*)whh0;    // [512][512]
                #pragma unroll 8
                for (int i = 0; i < nnzA; ++i) {
                    int k = s_idxA[i]; float dv = s_valA[i];
                    float4 w = hp[(k << 9) + j];
                    ar += dv * w.x; az += dv * w.y; anh += dv * w.z;
                }
            } else {
                #pragma unroll
                for (int f = 0; f < 6; ++f) {
                    float dv = s_dx0[f];
                    ar += dv * wih0[j * 6 + f];
                    az += dv * wih0[(HID + j) * 6 + f];
                    an += dv * wih0[(2*HID + j) * 6 + f];
                }
                for (int i = 0; i < nnzA; ++i) {
                    int k = s_idxA[i]; float dv = s_valA[i];
                    ar  += dv * whh0[j * HID + k];
                    az  += dv * whh0[(HID + j) * HID + k];
                    anh += dv * whh0[(2*HID + j) * HID + k];
                }
            }
            cr0 = ar; cz0 = az; cn0 = an; cnh0 = anh;
            float r = 1.f / (1.f + expf(-ar));
            float z = 1.f / (1.f + expf(-az));
            float n = tanhf(an + r * anh);
            h0 = (1.f - z) * n + z * h0;
        }

        // ---- layer1 deltas ----
        float dxv = h0 - xp1;
        if (fabsf(dxv) < THX) dxv = 0.f; else xp1 = h0;
        float dhv = h1 - h1p;
        if (fabsf(dhv) < THH) dhv = 0.f; else h1p = h1;
        unsigned long long mB = __ballot(dxv != 0.f);
        unsigned long long mC = __ballot(dhv != 0.f);
        if (lane == 0) { s_cnt[1][wid] = __popcll(mB); s_cnt[2][wid] = __popcll(mC); }
        __syncthreads();                                   // S3
        int baseB = 0, nnzB = 0, baseC = 0, nnzC = 0;
        #pragma unroll
        for (int w = 0; w < 8; ++w) {
            int cb = s_cnt[1][w], cc = s_cnt[2][w];
            baseB += (w < wid) ? cb : 0;  nnzB += cb;
            baseC += (w < wid) ? cc : 0;  nnzC += cc;
        }
        if (dxv != 0.f) {
            int pos = baseB + __popcll(mB & ((1ull << lane) - 1));
            s_idxB[pos] = j; s_valB[pos] = dxv;
        }
        if (dhv != 0.f) {
            int pos = baseC + __popcll(mC & ((1ull << lane) - 1));
            s_idxC[pos] = j; s_valC[pos] = dhv;
        }
        __syncthreads();                                   // S4

        // ---- layer1 MAC + gates ----
        {
            float ar = cr1, az = cz1, an = cn1, anh = cnh1;
            if (FAST) {
                const float4* xp = (const float4*)wih1;
                #pragma unroll 8
                for (int i = 0; i < nnzB; ++i) {
                    int k = s_idxB[i]; float dv = s_valB[i];
                    float4 w = xp[(k << 9) + j];
                    ar += dv * w.x; az += dv * w.y; an += dv * w.z;
                }
                const float4* hp = (const float4*)whh1;
                #pragma unroll 8
                for (int i = 0; i < nnzC; ++i) {
                    int k = s_idxC[i]; float dv = s_valC[i];
                    float4 w = hp[(k << 9) + j];
                    ar += dv * w.x; az += dv * w.y; anh += dv * w.z;
                }
            } else {
                for (int i = 0; i < nnzB; ++i) {
                    int k = s_idxB[i]; float dv = s_valB[i];
                    ar += dv * wih1[j * HID + k];
                    az += dv * wih1[(HID + j) * HID + k];
                    an += dv * wih1[(2*HID + j) * HID + k];
                }
                for (int i = 0; i < nnzC; ++i) {
                    int k = s_idxC[i]; float dv = s_valC[i];
                    ar  += dv * whh1[j * HID + k];
                    az  += dv * whh1[(HID + j) * HID + k];
                    anh += dv * whh1[(2*HID + j) * HID + k];
                }
            }
            cr1 = ar; cz1 = az; cn1 = an; cnh1 = anh;
            float r = 1.f / (1.f + expf(-ar));
            float z = 1.f / (1.f + expf(-az));
            float n = tanhf(an + r * anh);
            h1 = (1.f - z) * n + z * h1;
        }

        // ---- FC head ----
        float p0 = h1 * wfc0, p1 = h1 * wfc1;
        #pragma unroll
        for (int off = 32; off > 0; off >>= 1) {
            p0 += __shfl_down(p0, off, 64);
            p1 += __shfl_down(p1, off, 64);
        }
        if (lane == 0) { s_part[wid * 2] = p0; s_part[wid * 2 + 1] = p1; }
        __syncthreads();                                   // S5
        if (j == 0) {
            float o0 = bfc[0], o1 = bfc[1];
            #pragma unroll
            for (int w = 0; w < 8; ++w) { o0 += s_part[w * 2]; o1 += s_part[w * 2 + 1]; }
            out[(b * NT + t) * 2 + 0] = o0;
            out[(b * NT + t) * 2 + 1] = o1;
        }
        // no trailing barrier needed: next write to any LDS buffer is
        // separated from this iteration's readers by >=1 intervening barrier.
    }
}

extern "C" void kernel_launch(void* const* d_in, const int* in_sizes, int n_in,
                              void* d_out, int out_size, void* d_ws, size_t ws_size,
                              hipStream_t stream) {
    const float* x    = (const float*)d_in[0];
    // d_in[1] = h_0 : reference zero-inits h, input unused
    const float* wih0 = (const float*)d_in[2];
    const float* whh0 = (const float*)d_in[3];
    const float* bih0 = (const float*)d_in[4];
    const float* bhh0 = (const float*)d_in[5];
    const float* wih1 = (const float*)d_in[6];
    const float* whh1 = (const float*)d_in[7];
    const float* bih1 = (const float*)d_in[8];
    const float* bhh1 = (const float*)d_in[9];
    const float* wfc  = (const float*)d_in[10];
    const float* bfc  = (const float*)d_in[11];
    float* out = (float*)d_out;

    const size_t MAT4 = (size_t)HID * 2048 * sizeof(float);   // 4 MiB per packed matrix
    const size_t o_ih0 = 0;                                    // 6*2048*4 = 48 KiB
    const size_t o_hh0 = 6 * 2048 * sizeof(float);
    const size_t o_ih1 = o_hh0 + MAT4;
    const size_t o_hh1 = o_ih1 + MAT4;
    const size_t need  = o_hh1 + MAT4;                         // ~12.6 MiB

    if (ws_size >= need) {
        float* wt_ih0 = (float*)((char*)d_ws + o_ih0);
        float* wt_hh0 = (float*)((char*)d_ws + o_hh0);
        float* wt_ih1 = (float*)((char*)d_ws + o_ih1);
        float* wt_hh1 = (float*)((char*)d_ws + o_hh1);
        pack_ih0<<<(6 * HID + 255) / 256, 256, 0, stream>>>(wih0, wt_ih0);
        pack_h4<<<(HID * HID + 255) / 256, 256, 0, stream>>>(whh0, wt_hh0);
        pack_h4<<<(HID * HID + 255) / 256, 256, 0, stream>>>(wih1, wt_ih1);
        pack_h4<<<(HID * HID + 255) / 256, 256, 0, stream>>>(whh1, wt_hh1);
        dgru_kernel<true><<<NB, HID, 0, stream>>>(x, wt_ih0, wt_hh0, wt_ih1, wt_hh1,
                                                  bih0, bhh0, bih1, bhh1, wfc, bfc, out);
    } else {
        dgru_kernel<false><<<NB, HID, 0, stream>>>(x, wih0, whh0, wih1, whh1,
                                                   bih0, bhh0, bih1, bhh1, wfc, bfc, out);
    }
}